// Round 3
// baseline (28124.942 us; speedup 1.0000x reference)
//
#include <hip/hip_runtime.h>
#include <hip/hip_bf16.h>
#include <stdint.h>

// Output element offsets within d_out (element units of the output dtype):
// x:[64,10] @0, y:[64,512,32,32] @640, z:[64,512,16,16] @33555072, w:[64,512,8,8] @41943680
#define OFF0 0LL
#define OFFY 640LL
#define OFFZ 33555072LL
#define OFFW 41943680LL

// ---------------- dtype-flexible load/store ----------------

__device__ __forceinline__ float ldv(const void* p, long long i, int f32) {
    return f32 ? ((const float*)p)[i]
               : __bfloat162float(((const __hip_bfloat16*)p)[i]);
}

__device__ __forceinline__ void stv(void* p, long long i, float v, int f32) {
    if (!(v == v)) v = 0.0f;                 // sanitize NaN (paranoia)
    if (f32) ((float*)p)[i] = v;
    else     ((__hip_bfloat16*)p)[i] = __float2bfloat16(v);
}

// ---------------- fixed-point helpers (exact emulation of reference) ----------------

// fixq(x,16,14): clip(rint(x*2^14), -32768, 32767); rintf = half-even = jnp.round
__device__ __forceinline__ int fixq16(float x) {
    float r = rintf(x * 16384.0f);
    r = fminf(fmaxf(r, -32768.0f), 32767.0f);
    return (int)r;
}

// sign-magnitude 4-bit slices packed as 4 signed bytes in a dword (slice i in byte i)
__device__ __forceinline__ uint32_t pack_slices(int q) {
    int m = q < 0 ? -q : q;
    int b0 = m & 15, b1 = (m >> 4) & 15, b2 = (m >> 8) & 15, b3 = (m >> 12) & 15;
    if (q < 0) { b0 = -b0; b1 = -b1; b2 = -b2; b3 = -b3; }
    return ((uint32_t)(b0 & 255)) | ((uint32_t)(b1 & 255) << 8) |
           ((uint32_t)(b2 & 255) << 16) | ((uint32_t)(b3 & 255) << 24);
}

__device__ __forceinline__ uint32_t pack_f(float v) { return pack_slices(fixq16(v)); }

__device__ __forceinline__ int sx8(uint32_t v, int sh) {
    return (int)(signed char)(v >> sh);   // v_bfe_i32
}

// ADC clamp (+-2^13) each of 16 partials, shift-add 16^(s+t), /2^28,
// accumulator quantize: clip(rhe(out*2^24), +-2^31)/2^24. Exact integer emulation.
__device__ __forceinline__ float adc_acm_finish(const int* acc) {
    long long P = 0;
#pragma unroll
    for (int s = 0; s < 4; ++s)
#pragma unroll
        for (int t = 0; t < 4; ++t) {
            int p = acc[s * 4 + t];
            p = p < -8192 ? -8192 : (p > 8191 ? 8191 : p);
            P += ((long long)p) << (4 * (s + t));
        }
    long long base = P >> 4;                 // floor; r in [0,15]
    int r = (int)(P & 15);
    long long A = base + (r > 8 ? 1LL : (r == 8 ? (base & 1LL) : 0LL));
    if (A >  2147483647LL) A =  2147483647LL;
    if (A < -2147483648LL) A = -2147483648LL;
    return (float)A * (1.0f / 16777216.0f);
}

// ---------------- kernel 0: input dtype detection ----------------
// Interpret first 16384 halfwords of x as bf16; count exponent==0xFF.
// True bf16 N(0,1): 0 hits. float32 reinterpreted: ~64 expected hits.

__global__ __launch_bounds__(256) void detect_kernel(const void* __restrict__ x,
                                                     int* __restrict__ flag) {
    __shared__ int cnt;
    if (threadIdx.x == 0) cnt = 0;
    __syncthreads();
    const unsigned short* u = (const unsigned short*)x;
    int local = 0;
    for (int i = threadIdx.x; i < 16384; i += 256)
        if (((u[i] >> 7) & 0xFF) == 0xFF) local++;
    if (local) atomicAdd(&cnt, local);
    __syncthreads();
    if (threadIdx.x == 0) flag[0] = (cnt > 0) ? 1 : 0;   // 1 => inputs are float32
}

// ---------------- kernel 1: plain float conv1 (3->512, 3x3, pad1, stride1) ----------------

__global__ __launch_bounds__(256) void conv1_kernel(
    const void* __restrict__ x,    // [64,3,32,32]
    const void* __restrict__ w1,   // [512,3,3,3]
    void* __restrict__ dout,
    const int* __restrict__ flag)
{
    const int f32 = flag[0];
    long long idx = (long long)blockIdx.x * 256 + threadIdx.x;  // 33,554,432 exact
    int px = (int)(idx & 31), py = (int)((idx >> 5) & 31);
    int o  = (int)((idx >> 10) & 511), b = (int)(idx >> 19);
    long long xbase = (long long)b * 3072;
    long long wbase = (long long)o * 27;
    float acc = 0.0f;
#pragma unroll
    for (int c = 0; c < 3; ++c)
#pragma unroll
        for (int kh = 0; kh < 3; ++kh) {
            int iy = py - 1 + kh;
            if (iy < 0 || iy > 31) continue;
#pragma unroll
            for (int kw = 0; kw < 3; ++kw) {
                int ix = px - 1 + kw;
                if (ix < 0 || ix > 31) continue;
                acc += ldv(x, xbase + (c * 32 + iy) * 32 + ix, f32) *
                       ldv(w1, wbase + (c * 3 + kh) * 3 + kw, f32);
            }
        }
    stv(dout, OFFY + idx, acc, f32);
}

// ---------------- kernel 2: bit-sliced MVM conv (stride 2, pad 1, 512->512) ----------------

template <int IH, int OH>
__global__ __launch_bounds__(256) void mvm_conv_kernel(
    void* __restrict__ dout,            // activations read from dout+IN_OFF, written to dout+OUT_OFF
    const void* __restrict__ wsrc,      // [512,512,3,3] weights (bf16 or f32)
    long long IN_OFF, long long OUT_OFF,
    const int* __restrict__ flag)
{
    constexpr int IW = IH, OW = OH;
    constexpr int SP = OH * OW;          // 256 (conv2) / 64 (conv3)
    constexpr int SLOTS = 256 / SP;      // 1 / 4
    constexpr int OCT = 2;
    constexpr int NOC = SLOTS * OCT;     // 2 / 8
    constexpr int NPIX = IH * IW;
    constexpr int CCH = 8;

    __shared__ uint32_t xls[CCH * NPIX];        // 32 KB (conv2) / 8 KB (conv3)
    __shared__ uint32_t wls[NOC * CCH * 9];     // <= 2.3 KB

    const int f32 = flag[0];
    const int tid = threadIdx.x;
    const int sp = tid % SP;
    const int slot = tid / SP;
    const int b = blockIdx.y;
    const int oc0 = blockIdx.x * NOC;
    const int oy = sp / OW, ox = sp % OW;

    int acc[OCT][16];
#pragma unroll
    for (int j = 0; j < OCT; ++j)
#pragma unroll
        for (int i = 0; i < 16; ++i) acc[j][i] = 0;

    const long long xbase = IN_OFF + (long long)b * 512 * NPIX;

    for (int c0 = 0; c0 < 512; c0 += CCH) {
        for (int i = tid; i < CCH * NPIX; i += 256)
            xls[i] = pack_f(ldv(dout, xbase + (long long)c0 * NPIX + i, f32));
        for (int i = tid; i < NOC * CCH * 9; i += 256) {
            int ocl = i / (CCH * 9);
            int rem = i % (CCH * 9);
            int c = rem / 9, tap = rem % 9;
            wls[i] = pack_f(ldv(wsrc, (((long long)(oc0 + ocl)) * 512 + (c0 + c)) * 9 + tap, f32));
        }
        __syncthreads();

        for (int kh = 0; kh < 3; ++kh) {
            int iy = oy * 2 - 1 + kh;
            bool vy = (unsigned)iy < (unsigned)IH;
            for (int kw = 0; kw < 3; ++kw) {
                int ix = ox * 2 - 1 + kw;
                bool v = vy && ((unsigned)ix < (unsigned)IW);
                int pix = v ? iy * IW + ix : 0;
                int tap = kh * 3 + kw;
#pragma unroll
                for (int c = 0; c < CCH; ++c) {
                    uint32_t xp = xls[c * NPIX + pix];
                    if (!v) xp = 0u;
                    int xv[4];
                    xv[0] = sx8(xp, 0); xv[1] = sx8(xp, 8);
                    xv[2] = sx8(xp, 16); xv[3] = sx8(xp, 24);
#pragma unroll
                    for (int j = 0; j < OCT; ++j) {
                        uint32_t wp = wls[((slot * OCT + j) * CCH + c) * 9 + tap];
                        int wv[4];
                        wv[0] = sx8(wp, 0); wv[1] = sx8(wp, 8);
                        wv[2] = sx8(wp, 16); wv[3] = sx8(wp, 24);
#pragma unroll
                        for (int s = 0; s < 4; ++s)
#pragma unroll
                            for (int t = 0; t < 4; ++t)
                                acc[j][s * 4 + t] += __mul24(xv[s], wv[t]); // v_mad_i32_i24
                    }
                }
            }
        }
        __syncthreads();
    }

#pragma unroll
    for (int j = 0; j < OCT; ++j) {
        int oc = oc0 + slot * OCT + j;
        float zf = adc_acm_finish(acc[j]);
        stv(dout, OUT_OFF + (((long long)b * 512 + oc) * OH + oy) * OW + ox, zf, f32);
    }
}

// ---------------- kernel 3: avgpool(6x6 of 8x8) + bit-sliced linear ----------------

__global__ __launch_bounds__(256) void linear_kernel(
    void* __restrict__ dout,
    const void* __restrict__ wlin,            // [10,512]
    const int* __restrict__ flag)
{
    __shared__ uint32_t xq[512];
    const int f32 = flag[0];
    int b = blockIdx.x, tid = threadIdx.x;
    for (int c = tid; c < 512; c += 256) {
        long long base = OFFW + ((long long)b * 512 + c) * 64;
        float s = 0.0f;
#pragma unroll
        for (int i = 0; i < 6; ++i)
#pragma unroll
            for (int jj = 0; jj < 6; ++jj) s += ldv(dout, base + i * 8 + jj, f32);
        xq[c] = pack_f(s / 36.0f);
    }
    __syncthreads();
    if (tid < 10) {
        int acc[16];
#pragma unroll
        for (int i = 0; i < 16; ++i) acc[i] = 0;
        for (int k = 0; k < 512; ++k) {
            uint32_t xp = xq[k];
            uint32_t wp = pack_f(ldv(wlin, tid * 512 + k, f32));
            int xv[4], wv[4];
            xv[0] = sx8(xp, 0); xv[1] = sx8(xp, 8); xv[2] = sx8(xp, 16); xv[3] = sx8(xp, 24);
            wv[0] = sx8(wp, 0); wv[1] = sx8(wp, 8); wv[2] = sx8(wp, 16); wv[3] = sx8(wp, 24);
#pragma unroll
            for (int s = 0; s < 4; ++s)
#pragma unroll
                for (int t = 0; t < 4; ++t)
                    acc[s * 4 + t] += __mul24(xv[s], wv[t]);
        }
        stv(dout, OFF0 + b * 10 + tid, adc_acm_finish(acc), f32);
    }
}

// ---------------- launch ----------------

extern "C" void kernel_launch(void* const* d_in, const int* in_sizes, int n_in,
                              void* d_out, int out_size, void* d_ws, size_t ws_size,
                              hipStream_t stream) {
    const void* x    = d_in[0];
    const void* w1   = d_in[1];
    const void* w2   = d_in[2];
    const void* w3   = d_in[3];
    const void* wlin = d_in[4];
    int* flag = (int*)d_ws;     // 4 bytes of workspace, rewritten every launch

    detect_kernel<<<1, 256, 0, stream>>>(x, flag);
    conv1_kernel<<<131072, 256, 0, stream>>>(x, w1, d_out, flag);
    // conv2: [64,512,32,32] -> [64,512,16,16]
    mvm_conv_kernel<32, 16><<<dim3(256, 64), 256, 0, stream>>>(d_out, w2, OFFY, OFFZ, flag);
    // conv3: [64,512,16,16] -> [64,512,8,8]
    mvm_conv_kernel<16, 8><<<dim3(64, 64), 256, 0, stream>>>(d_out, w3, OFFZ, OFFW, flag);
    linear_kernel<<<64, 256, 0, stream>>>(d_out, wlin, flag);
}

// Round 4
// 2339.853 us; speedup vs baseline: 12.0200x; 12.0200x over previous
//
#include <hip/hip_runtime.h>
#include <hip/hip_bf16.h>
#include <stdint.h>

typedef int i32x4 __attribute__((ext_vector_type(4)));

// Output element offsets within d_out (element units of output dtype):
#define OFF0 0LL
#define OFFY 640LL
#define OFFZ 33555072LL
#define OFFW 41943680LL

// workspace byte offsets (fast path)
#define WS_FLAG  0LL
#define WS_XP2   256LL                        // [4][64][1024][512] i8 = 134,217,728
#define WS_XP3   (WS_XP2 + 134217728LL)       // [4][64][256][512]  i8 =  33,554,432
#define WS_WP2   (WS_XP3 + 33554432LL)        // [8][9][8][16384]   i8 =   9,437,184
#define WS_WP3   (WS_WP2 + 9437184LL)
#define WS_END   (WS_WP3 + 9437184LL)         // 186,646,784

// ---------------- dtype-flexible load/store ----------------

__device__ __forceinline__ float ldv(const void* p, long long i, int f32) {
    return f32 ? ((const float*)p)[i]
               : __bfloat162float(((const __hip_bfloat16*)p)[i]);
}

__device__ __forceinline__ void stv(void* p, long long i, float v, int f32) {
    if (!(v == v)) v = 0.0f;
    if (f32) ((float*)p)[i] = v;
    else     ((__hip_bfloat16*)p)[i] = __float2bfloat16(v);
}

// ---------------- fixed-point helpers (exact emulation of reference) ----------------

__device__ __forceinline__ int fixq16(float x) {
    float r = rintf(x * 16384.0f);
    r = fminf(fmaxf(r, -32768.0f), 32767.0f);
    return (int)r;
}

// sign-magnitude 4-bit slices packed as 4 signed bytes in a dword (slice i in byte i)
__device__ __forceinline__ uint32_t pack_slices(int q) {
    int m = q < 0 ? -q : q;
    int b0 = m & 15, b1 = (m >> 4) & 15, b2 = (m >> 8) & 15, b3 = (m >> 12) & 15;
    if (q < 0) { b0 = -b0; b1 = -b1; b2 = -b2; b3 = -b3; }
    return ((uint32_t)(b0 & 255)) | ((uint32_t)(b1 & 255) << 8) |
           ((uint32_t)(b2 & 255) << 16) | ((uint32_t)(b3 & 255) << 24);
}

__device__ __forceinline__ uint32_t pack_f(float v) { return pack_slices(fixq16(v)); }

__device__ __forceinline__ int sx8(uint32_t v, int sh) {
    return (int)(signed char)(v >> sh);
}

// 4x4 byte transpose: q[r] holds bytes (slice0..3) of value r; r4[s] = bytes (q0.s..q3.s)
__device__ __forceinline__ void transpose4(const uint32_t* q, uint32_t* r4) {
    uint32_t lo01 = __builtin_amdgcn_perm(q[1], q[0], 0x05040100u); // q0s0 q0s1 q1s0 q1s1
    uint32_t hi01 = __builtin_amdgcn_perm(q[1], q[0], 0x07060302u); // q0s2 q0s3 q1s2 q1s3
    uint32_t lo23 = __builtin_amdgcn_perm(q[3], q[2], 0x05040100u);
    uint32_t hi23 = __builtin_amdgcn_perm(q[3], q[2], 0x07060302u);
    r4[0] = __builtin_amdgcn_perm(lo23, lo01, 0x06040200u);
    r4[1] = __builtin_amdgcn_perm(lo23, lo01, 0x07050301u);
    r4[2] = __builtin_amdgcn_perm(hi23, hi01, 0x06040200u);
    r4[3] = __builtin_amdgcn_perm(hi23, hi01, 0x07050301u);
}

// ADC clamp each of 16 partials, shift-add 16^(s+t), /2^28, acm quantize. Exact.
__device__ __forceinline__ float adc_acm_finish(const int* acc) {
    long long P = 0;
#pragma unroll
    for (int s = 0; s < 4; ++s)
#pragma unroll
        for (int t = 0; t < 4; ++t) {
            int p = acc[s * 4 + t];
            p = p < -8192 ? -8192 : (p > 8191 ? 8191 : p);
            P += ((long long)p) << (4 * (s + t));
        }
    long long base = P >> 4;
    int r = (int)(P & 15);
    long long A = base + (r > 8 ? 1LL : (r == 8 ? (base & 1LL) : 0LL));
    if (A >  2147483647LL) A =  2147483647LL;
    if (A < -2147483648LL) A = -2147483648LL;
    return (float)A * (1.0f / 16777216.0f);
}

// ---------------- kernel 0: input dtype detection ----------------

__global__ __launch_bounds__(256) void detect_kernel(const void* __restrict__ x,
                                                     int* __restrict__ flag) {
    __shared__ int cnt;
    if (threadIdx.x == 0) cnt = 0;
    __syncthreads();
    const unsigned short* u = (const unsigned short*)x;
    int local = 0;
    for (int i = threadIdx.x; i < 16384; i += 256)
        if (((u[i] >> 7) & 0xFF) == 0xFF) local++;
    if (local) atomicAdd(&cnt, local);
    __syncthreads();
    if (threadIdx.x == 0) flag[0] = (cnt > 0) ? 1 : 0;   // 1 => float32
}

// ---------------- kernel 1: plain float conv1 ----------------

__global__ __launch_bounds__(256) void conv1_kernel(
    const void* __restrict__ x, const void* __restrict__ w1,
    void* __restrict__ dout, const int* __restrict__ flag)
{
    const int f32 = flag[0];
    long long idx = (long long)blockIdx.x * 256 + threadIdx.x;
    int px = (int)(idx & 31), py = (int)((idx >> 5) & 31);
    int o  = (int)((idx >> 10) & 511), b = (int)(idx >> 19);
    long long xbase = (long long)b * 3072;
    long long wbase = (long long)o * 27;
    float acc = 0.0f;
#pragma unroll
    for (int c = 0; c < 3; ++c)
#pragma unroll
        for (int kh = 0; kh < 3; ++kh) {
            int iy = py - 1 + kh;
            if (iy < 0 || iy > 31) continue;
#pragma unroll
            for (int kw = 0; kw < 3; ++kw) {
                int ix = px - 1 + kw;
                if (ix < 0 || ix > 31) continue;
                acc += ldv(x, xbase + (c * 32 + iy) * 32 + ix, f32) *
                       ldv(w1, wbase + (c * 3 + kh) * 3 + kw, f32);
            }
        }
    stv(dout, OFFY + idx, acc, f32);
}

// ---------------- prep: y -> slice planes [s][b][1024 pix][512 ic] ----------------
// block: (pt: 8 p-tiles of 128, ict: 8 ic-tiles of 64, b: 64)

__global__ __launch_bounds__(256) void prep_x2_kernel(
    const void* __restrict__ dout, signed char* __restrict__ xp2,
    const int* __restrict__ flag)
{
    __shared__ uint32_t lt[64][129];
    const int f32 = flag[0];
    const int pt = blockIdx.x, ict = blockIdx.y, b = blockIdx.z;
    const int tid = threadIdx.x;
    for (int it = 0; it < 8; ++it) {
        int ic_r = it * 8 + (tid >> 5);
        int c4 = (tid & 31) * 4;
        long long src = OFFY + ((long long)(b * 512 + ict * 64 + ic_r)) * 1024 + pt * 128 + c4;
#pragma unroll
        for (int j = 0; j < 4; ++j)
            lt[ic_r][c4 + j] = pack_f(ldv(dout, src + j, f32));
    }
    __syncthreads();
    for (int it = 0; it < 2; ++it) {
        int item = it * 256 + tid;
        int g = item & 3;          // ic 16-group within tile
        int p_l = item >> 2;       // 0..127
        uint32_t q[16];
#pragma unroll
        for (int j = 0; j < 16; ++j) q[j] = lt[g * 16 + j][p_l];
        uint32_t r4[4][4];
#pragma unroll
        for (int d = 0; d < 4; ++d) transpose4(&q[d * 4], r4[d]);
#pragma unroll
        for (int s = 0; s < 4; ++s) {
            long long dst = (((long long)(s * 64 + b)) * 1024 + pt * 128 + p_l) * 512
                            + ict * 64 + g * 16;
            i32x4 v = { (int)r4[0][s], (int)r4[1][s], (int)r4[2][s], (int)r4[3][s] };
            *(i32x4*)(xp2 + dst) = v;
        }
    }
}

// ---------------- prep: weights -> LDS-round-ordered slabs ----------------
// wp layout: [ocb 8][tap 9][chunk 8] rounds of 16384 B = [t 4][kg 4][oc 64][16 B]

__global__ __launch_bounds__(256) void prep_w_kernel(
    const void* __restrict__ w, signed char* __restrict__ wp,
    const int* __restrict__ flag)
{
    const int f32 = flag[0];
    int item = blockIdx.x * 256 + threadIdx.x;     // 147,456 exact
    int icg = item & 31;
    int tap = (item >> 5) % 9;
    int oc = item / 288;
    uint32_t q[16];
#pragma unroll
    for (int j = 0; j < 16; ++j)
        q[j] = pack_f(ldv(w, ((long long)oc * 512 + icg * 16 + j) * 9 + tap, f32));
    uint32_t r4[4][4];
#pragma unroll
    for (int d = 0; d < 4; ++d) transpose4(&q[d * 4], r4[d]);
    int chunk = icg >> 2, kg = icg & 3, ocb = oc >> 6, oc_l = oc & 63;
#pragma unroll
    for (int t = 0; t < 4; ++t) {
        long long dst = ((long long)((ocb * 9 + tap) * 8 + chunk)) * 16384
                        + ((t * 4 + kg) * 64 + oc_l) * 16;
        i32x4 v = { (int)r4[0][t], (int)r4[1][t], (int)r4[2][t], (int)r4[3][t] };
        *(i32x4*)(wp + dst) = v;
    }
}

// ---------------- MFMA bit-sliced MVM conv (stride 2, pad 1, 512->512) ----------------
// Wave: 16oc x 16pix tile, 16 (s,t) int32 accs. Block: 4 waves = 64 oc.
// A (weights) via double-buffered LDS rounds; B (act slices) direct global dwordx4.

template <int IH, int OH>
__global__ __launch_bounds__(256) void mvm_mfma_kernel(
    const signed char* __restrict__ xp,   // [4][64][IH*IH][512]
    const signed char* __restrict__ wp,   // rounds
    void* __restrict__ dout, long long OUT_OFF,
    signed char* __restrict__ xp_next,    // conv3 planes or nullptr
    const int* __restrict__ flag)
{
    constexpr int NPIX = IH * IH;
    constexpr int NPIXO = OH * OH;
    __shared__ signed char als[2][16384];
    const int f32 = flag[0];
    const int tid = threadIdx.x;
    const int w = tid >> 6;
    const int lane = tid & 63;
    const int n = lane & 15;
    const int kg = lane >> 4;
    const int mblk = blockIdx.x;
    const int b = blockIdx.z;
    int oy, ox;
    if (OH == 16) { oy = blockIdx.y;                  ox = n; }
    else          { oy = blockIdx.y * 2 + (n >> 3);   ox = n & 7; }

    const signed char* wpb = wp + (long long)mblk * (9LL * 8 * 16384);

    // initial stage: round 0 -> als[0]
    {
        const i32x4* s0 = (const i32x4*)wpb;
        i32x4* dl = (i32x4*)&als[0][0];
        dl[tid] = s0[tid]; dl[256 + tid] = s0[256 + tid];
        dl[512 + tid] = s0[512 + tid]; dl[768 + tid] = s0[768 + tid];
    }

    i32x4 acc[16] = {};
    long long bbase[4];
#pragma unroll
    for (int s = 0; s < 4; ++s) bbase[s] = (((long long)(s * 64 + b)) * NPIX) * 512;

    int cur = 0;
    for (int tap = 0; tap < 9; ++tap) {
        int kh = tap / 3, kw = tap % 3;
        int iy = oy * 2 - 1 + kh;
        int ix = ox * 2 - 1 + kw;
        bool val = ((unsigned)iy < (unsigned)IH) && ((unsigned)ix < (unsigned)IH);
        long long pofs = (long long)(iy * IH + ix) * 512 + kg * 16;
        for (int chunk = 0; chunk < 8; ++chunk) {
            int r = tap * 8 + chunk;
            __syncthreads();
            i32x4 t0, t1, t2, t3;
            bool hn = (r + 1 < 72);
            if (hn) {
                const i32x4* s2 = (const i32x4*)(wpb + (long long)(r + 1) * 16384);
                t0 = s2[tid]; t1 = s2[256 + tid]; t2 = s2[512 + tid]; t3 = s2[768 + tid];
            }
            i32x4 bfr[4];
#pragma unroll
            for (int s = 0; s < 4; ++s) {
                i32x4 z = {};
                bfr[s] = val ? *(const i32x4*)(xp + bbase[s] + pofs + chunk * 64) : z;
            }
            const signed char* ab = als[cur];
#pragma unroll
            for (int t = 0; t < 4; ++t) {
                i32x4 af = *(const i32x4*)(ab + ((t * 4 + kg) * 64 + (w * 16 + n)) * 16);
#pragma unroll
                for (int s = 0; s < 4; ++s)
                    acc[s * 4 + t] = __builtin_amdgcn_mfma_i32_16x16x64_i8(
                        af, bfr[s], acc[s * 4 + t], 0, 0, 0);
            }
            if (hn) {
                i32x4* dl = (i32x4*)&als[cur ^ 1][0];
                dl[tid] = t0; dl[256 + tid] = t1; dl[512 + tid] = t2; dl[768 + tid] = t3;
            }
            cur ^= 1;
        }
    }

    // epilogue: C/D col = lane&15 (pixel), row = kg*4 + reg (oc)
    int p_out = oy * OH + ox;
    int oc0 = mblk * 64 + w * 16 + kg * 4;
    int qv[4];
#pragma unroll
    for (int r = 0; r < 4; ++r) {
        int parts[16];
#pragma unroll
        for (int st = 0; st < 16; ++st) parts[st] = acc[st][r];
        float zf = adc_acm_finish(parts);
        stv(dout, OUT_OFF + ((long long)(b * 512 + oc0 + r)) * NPIXO + p_out, zf, f32);
        qv[r] = fixq16(zf);
    }
    if (xp_next) {
        uint32_t pk[4], r4[4];
#pragma unroll
        for (int r = 0; r < 4; ++r) pk[r] = pack_slices(qv[r]);
        transpose4(pk, r4);
#pragma unroll
        for (int s = 0; s < 4; ++s)
            *(uint32_t*)(xp_next + (((long long)(s * 64 + b)) * NPIXO + p_out) * 512 + oc0) = r4[s];
    }
}

// ---------------- slow-path fallback (round-3, proven) ----------------

template <int IH, int OH>
__global__ __launch_bounds__(256) void mvm_conv_kernel(
    void* __restrict__ dout, const void* __restrict__ wsrc,
    long long IN_OFF, long long OUT_OFF, const int* __restrict__ flag)
{
    constexpr int IW = IH, OW = OH;
    constexpr int SP = OH * OW;
    constexpr int SLOTS = 256 / SP;
    constexpr int OCT = 2;
    constexpr int NOC = SLOTS * OCT;
    constexpr int NPIX = IH * IW;
    constexpr int CCH = 8;
    __shared__ uint32_t xls[CCH * NPIX];
    __shared__ uint32_t wls[NOC * CCH * 9];
    const int f32 = flag[0];
    const int tid = threadIdx.x;
    const int sp = tid % SP;
    const int slot = tid / SP;
    const int b = blockIdx.y;
    const int oc0 = blockIdx.x * NOC;
    const int oy = sp / OW, ox = sp % OW;
    int acc[OCT][16];
#pragma unroll
    for (int j = 0; j < OCT; ++j)
#pragma unroll
        for (int i = 0; i < 16; ++i) acc[j][i] = 0;
    const long long xbase = IN_OFF + (long long)b * 512 * NPIX;
    for (int c0 = 0; c0 < 512; c0 += CCH) {
        for (int i = tid; i < CCH * NPIX; i += 256)
            xls[i] = pack_f(ldv(dout, xbase + (long long)c0 * NPIX + i, f32));
        for (int i = tid; i < NOC * CCH * 9; i += 256) {
            int ocl = i / (CCH * 9);
            int rem = i % (CCH * 9);
            int c = rem / 9, tap = rem % 9;
            wls[i] = pack_f(ldv(wsrc, (((long long)(oc0 + ocl)) * 512 + (c0 + c)) * 9 + tap, f32));
        }
        __syncthreads();
        for (int kh = 0; kh < 3; ++kh) {
            int iy = oy * 2 - 1 + kh;
            bool vy = (unsigned)iy < (unsigned)IH;
            for (int kw = 0; kw < 3; ++kw) {
                int ix = ox * 2 - 1 + kw;
                bool v = vy && ((unsigned)ix < (unsigned)IW);
                int pix = v ? iy * IW + ix : 0;
                int tap = kh * 3 + kw;
#pragma unroll
                for (int c = 0; c < CCH; ++c) {
                    uint32_t xpk = xls[c * NPIX + pix];
                    if (!v) xpk = 0u;
                    int xv[4];
                    xv[0] = sx8(xpk, 0); xv[1] = sx8(xpk, 8);
                    xv[2] = sx8(xpk, 16); xv[3] = sx8(xpk, 24);
#pragma unroll
                    for (int j = 0; j < OCT; ++j) {
                        uint32_t wpk = wls[((slot * OCT + j) * CCH + c) * 9 + tap];
                        int wv[4];
                        wv[0] = sx8(wpk, 0); wv[1] = sx8(wpk, 8);
                        wv[2] = sx8(wpk, 16); wv[3] = sx8(wpk, 24);
#pragma unroll
                        for (int s = 0; s < 4; ++s)
#pragma unroll
                            for (int t = 0; t < 4; ++t)
                                acc[j][s * 4 + t] += __mul24(xv[s], wv[t]);
                    }
                }
            }
        }
        __syncthreads();
    }
#pragma unroll
    for (int j = 0; j < OCT; ++j) {
        int oc = oc0 + slot * OCT + j;
        float zf = adc_acm_finish(acc[j]);
        stv(dout, OUT_OFF + (((long long)b * 512 + oc) * OH + oy) * OW + ox, zf, f32);
    }
}

// ---------------- avgpool(6x6 of 8x8) + bit-sliced linear ----------------

__global__ __launch_bounds__(256) void linear_kernel(
    void* __restrict__ dout, const void* __restrict__ wlin,
    const int* __restrict__ flag)
{
    __shared__ uint32_t xq[512];
    const int f32 = flag[0];
    int b = blockIdx.x, tid = threadIdx.x;
    for (int c = tid; c < 512; c += 256) {
        long long base = OFFW + ((long long)b * 512 + c) * 64;
        float s = 0.0f;
#pragma unroll
        for (int i = 0; i < 6; ++i)
#pragma unroll
            for (int jj = 0; jj < 6; ++jj) s += ldv(dout, base + i * 8 + jj, f32);
        xq[c] = pack_f(s / 36.0f);
    }
    __syncthreads();
    if (tid < 10) {
        int acc[16];
#pragma unroll
        for (int i = 0; i < 16; ++i) acc[i] = 0;
        for (int k = 0; k < 512; ++k) {
            uint32_t xpk = xq[k];
            uint32_t wpk = pack_f(ldv(wlin, tid * 512 + k, f32));
            int xv[4], wv[4];
            xv[0] = sx8(xpk, 0); xv[1] = sx8(xpk, 8); xv[2] = sx8(xpk, 16); xv[3] = sx8(xpk, 24);
            wv[0] = sx8(wpk, 0); wv[1] = sx8(wpk, 8); wv[2] = sx8(wpk, 16); wv[3] = sx8(wpk, 24);
#pragma unroll
            for (int s = 0; s < 4; ++s)
#pragma unroll
                for (int t = 0; t < 4; ++t)
                    acc[s * 4 + t] += __mul24(xv[s], wv[t]);
        }
        stv(dout, OFF0 + b * 10 + tid, adc_acm_finish(acc), f32);
    }
}

// ---------------- launch ----------------

extern "C" void kernel_launch(void* const* d_in, const int* in_sizes, int n_in,
                              void* d_out, int out_size, void* d_ws, size_t ws_size,
                              hipStream_t stream) {
    const void* x    = d_in[0];
    const void* w1   = d_in[1];
    const void* w2   = d_in[2];
    const void* w3   = d_in[3];
    const void* wlin = d_in[4];
    char* ws = (char*)d_ws;
    int* flag = (int*)(ws + WS_FLAG);

    detect_kernel<<<1, 256, 0, stream>>>(x, flag);
    conv1_kernel<<<131072, 256, 0, stream>>>(x, w1, d_out, flag);

    if (ws_size >= (size_t)WS_END) {
        signed char* xp2 = (signed char*)(ws + WS_XP2);
        signed char* xp3 = (signed char*)(ws + WS_XP3);
        signed char* wp2 = (signed char*)(ws + WS_WP2);
        signed char* wp3 = (signed char*)(ws + WS_WP3);
        prep_x2_kernel<<<dim3(8, 8, 64), 256, 0, stream>>>(d_out, xp2, flag);
        prep_w_kernel<<<576, 256, 0, stream>>>(w2, wp2, flag);
        prep_w_kernel<<<576, 256, 0, stream>>>(w3, wp3, flag);
        mvm_mfma_kernel<32, 16><<<dim3(8, 16, 64), 256, 0, stream>>>(
            xp2, wp2, d_out, OFFZ, xp3, flag);
        mvm_mfma_kernel<16, 8><<<dim3(8, 4, 64), 256, 0, stream>>>(
            xp3, wp3, d_out, OFFW, nullptr, flag);
    } else {
        mvm_conv_kernel<32, 16><<<dim3(256, 64), 256, 0, stream>>>(d_out, w2, OFFY, OFFZ, flag);
        mvm_conv_kernel<16, 8><<<dim3(64, 64), 256, 0, stream>>>(d_out, w3, OFFZ, OFFW, flag);
    }
    linear_kernel<<<64, 256, 0, stream>>>(d_out, wlin, flag);
}